// Round 8
// baseline (853.354 us; speedup 1.0000x reference)
//
#include <hip/hip_runtime.h>
#include <float.h>
#include <math.h>

#define BB   2
#define NPTS 2048
#define NODES (BB*NPTS)   // 4096
#define NNB  32
#define NH   4
#define NDH  64

// padded LDS row strides (== 4 mod 32 words -> conflict-free broadcast groups)
#define SCR_LD  132
#define POS_LD   68
#define M_LD     68
#define E2T_LD  132

// ======================= KNN (exact numpy replication) =======================
__global__ __launch_bounds__(256) void knn_kernel(const float* __restrict__ coors,
    int* __restrict__ idx_out, float* __restrict__ dnb_out, float* __restrict__ rel_out) {
#pragma clang fp contract(off)
  const int node = blockIdx.x;
  const int b = node >> 11;
  const int i = node & (NPTS - 1);
  __shared__ float cx[NPTS], cy[NPTS], cz[NPTS];
  __shared__ float wdist[4]; __shared__ int wjj[4];
  __shared__ float win_d_s; __shared__ int win_j_s;
  __shared__ float sel_d[NNB]; __shared__ int sel_j[NNB];
  const float* cb = coors + (size_t)b * NPTS * 3;
  for (int j = threadIdx.x; j < NPTS; j += 256) {
    cx[j] = cb[3*j]; cy[j] = cb[3*j+1]; cz[j] = cb[3*j+2];
  }
  __syncthreads();
  const float xi = cx[i], yi = cy[i], zi = cz[i];
  float dl[8]; int jl[8];
  #pragma unroll
  for (int s = 0; s < 8; ++s) {
    int j = threadIdx.x + (s << 8);
    float dx = xi - cx[j];
    float dy = yi - cy[j];
    float dz = zi - cz[j];
    float ss = dx*dx + dy*dy;   // contract(off): matches numpy rounding
    ss = ss + dz*dz;
    dl[s] = sqrtf(ss);          // correctly rounded by default on HIP
    jl[s] = j;
  }
  for (int it = 0; it < NNB; ++it) {
    float bd = FLT_MAX; int bj = 0x7FFFFFFF;
    #pragma unroll
    for (int s = 0; s < 8; ++s)
      if (dl[s] < bd || (dl[s] == bd && jl[s] < bj)) { bd = dl[s]; bj = jl[s]; }
    #pragma unroll
    for (int off = 32; off > 0; off >>= 1) {
      float od = __shfl_down(bd, off, 64);
      int   oj = __shfl_down(bj, off, 64);
      if (od < bd || (od == bd && oj < bj)) { bd = od; bj = oj; }
    }
    if ((threadIdx.x & 63) == 0) { wdist[threadIdx.x >> 6] = bd; wjj[threadIdx.x >> 6] = bj; }
    __syncthreads();
    if (threadIdx.x == 0) {
      float fd = wdist[0]; int fj = wjj[0];
      #pragma unroll
      for (int w = 1; w < 4; ++w)
        if (wdist[w] < fd || (wdist[w] == fd && wjj[w] < fj)) { fd = wdist[w]; fj = wjj[w]; }
      win_d_s = fd; win_j_s = fj; sel_d[it] = fd; sel_j[it] = fj;
    }
    __syncthreads();
    const int wj = win_j_s;
    #pragma unroll
    for (int s = 0; s < 8; ++s) if (jl[s] == wj) dl[s] = FLT_MAX;
    __syncthreads();
  }
  if (threadIdx.x < NNB) {
    int s = threadIdx.x;
    int j = sel_j[s];
    idx_out[(size_t)node*NNB + s] = j;
    dnb_out[(size_t)node*NNB + s] = sel_d[s];
    float* rp = rel_out + ((size_t)node*NNB + s)*3;
    rp[0] = xi - cx[j]; rp[1] = yi - cy[j]; rp[2] = zi - cz[j];
  }
}

// ======================= generic f32 GEMM (64x64 tile) =======================
template<bool SPLIT>
__global__ __launch_bounds__(256) void gemm_kernel(const float* __restrict__ A,
    const float* __restrict__ Bm, const float* __restrict__ bias,
    float* __restrict__ C0, float* __restrict__ C1, float* __restrict__ C2,
    int Mn, int Nn, int Kn, int lda, int ldb) {
  __shared__ float As[64][17];
  __shared__ __align__(16) float Bs[16][64];
  const int bm = blockIdx.x * 64, bn = blockIdx.y * 64;
  const int tx = threadIdx.x & 15, ty = threadIdx.x >> 4;
  const int lm = threadIdx.x >> 2, lk = (threadIdx.x & 3) * 4;
  const int br = threadIdx.x >> 4, bc = (threadIdx.x & 15) * 4;
  float acc[4][4] = {};
  for (int k0 = 0; k0 < Kn; k0 += 16) {
    float4 av = *(const float4*)(A + (size_t)(bm + lm)*lda + k0 + lk);
    As[lm][lk+0] = av.x; As[lm][lk+1] = av.y; As[lm][lk+2] = av.z; As[lm][lk+3] = av.w;
    float4 bv = *(const float4*)(Bm + (size_t)(k0 + br)*ldb + bn + bc);
    *(float4*)&Bs[br][bc] = bv;
    __syncthreads();
    #pragma unroll
    for (int kk = 0; kk < 16; ++kk) {
      float a0 = As[ty*4+0][kk], a1 = As[ty*4+1][kk], a2 = As[ty*4+2][kk], a3 = As[ty*4+3][kk];
      float4 bq = *(const float4*)&Bs[kk][tx*4];
      acc[0][0] += a0*bq.x; acc[0][1] += a0*bq.y; acc[0][2] += a0*bq.z; acc[0][3] += a0*bq.w;
      acc[1][0] += a1*bq.x; acc[1][1] += a1*bq.y; acc[1][2] += a1*bq.z; acc[1][3] += a1*bq.w;
      acc[2][0] += a2*bq.x; acc[2][1] += a2*bq.y; acc[2][2] += a2*bq.z; acc[2][3] += a2*bq.w;
      acc[3][0] += a3*bq.x; acc[3][1] += a3*bq.y; acc[3][2] += a3*bq.z; acc[3][3] += a3*bq.w;
    }
    __syncthreads();
  }
  #pragma unroll
  for (int r = 0; r < 4; ++r) {
    #pragma unroll
    for (int c = 0; c < 4; ++c) {
      int row = bm + ty*4 + r, col = bn + tx*4 + c;
      float vv = acc[r][c];
      if (bias) vv += bias[col];
      if (SPLIT) {
        int w = col >> 8, cc = col & 255;
        float* Cp = (w == 0) ? C0 : ((w == 1) ? C1 : C2);
        Cp[(size_t)row*256 + cc] = vv;
      } else {
        C0[(size_t)row*Nn + col] = vv;
      }
    }
  }
}

// ======================= fused per-node kernel =======================
// block = one node, 512 threads. 53,888 B dynamic LDS -> 3 blocks/CU.
// pose lives in registers (P2 mapping == P3 consumer mapping).
// w_p1 / w_p2 / w_e1 / w_c1 / biases read from global (L1-resident broadcast).
__global__ __launch_bounds__(512, 6) void fused_kernel(
    const int* __restrict__ idx, const float* __restrict__ dnb, const float* __restrict__ relnb,
    const float* __restrict__ qe, const float* __restrict__ ke, const float* __restrict__ v,
    const float* __restrict__ w_p1, const float* __restrict__ b_p1,
    const float* __restrict__ w_p2, const float* __restrict__ b_p2,
    const float* __restrict__ w_e1, const float* __restrict__ w_e2, const float* __restrict__ b_e2,
    const float* __restrict__ w_a1, const float* __restrict__ b_a1,
    const float* __restrict__ w_a2, const float* __restrict__ b_a2,
    const float* __restrict__ w_c1, const float* __restrict__ b_c1,
    const float* __restrict__ w_c2, const float* __restrict__ b_c2,
    float* __restrict__ hsum, float* __restrict__ coors_out) {
  extern __shared__ float sm[];
  float* w_e2Ts= sm;               // 16*132 = 2112 (transposed)
  float* w_a1s = w_e2Ts + 2112;    // 1024
  float* qe_s  = w_a1s + 1024;     // 512
  float* fe_s  = qe_s + 512;       // 288
  float* pos_s = fe_s + 288;       // 32*68  = 2176
  float* scr   = pos_s + 2176;     // 32*132 = 4224 (ph / h1e / ch)
  float* m_all = scr + 4224;       // 32*68  = 2176
  float* sim_s = m_all + 2176;     // 128
  float* attn_s= sim_s + 128;      // 128
  float* part_s= attn_s + 128;     // 512
  float* cw_s  = part_s + 512;     // 32
  float* dnb_s = cw_s + 32;        // 32
  float* rel_s = dnb_s + 32;       // 96
  int*   idx_s = (int*)(rel_s + 96); // 32  -> total 13472 floats = 53,888 B
  const int t = threadIdx.x;
  const int node = blockIdx.x;
  const int b = node >> 11;

  // ---- stage LDS-resident data ----
  for (int i = t; i < 2048; i += 512) {            // transpose w_e2 [128][16] -> [16][132]
    int kx = i >> 4, mt = i & 15;
    w_e2Ts[mt*E2T_LD + kx] = w_e2[i];
  }
  for (int i = t; i < 1024; i += 512) w_a1s[i] = w_a1[i];
  qe_s[t] = qe[(size_t)node*512 + t];
  if (t < NNB) { idx_s[t] = idx[(size_t)node*NNB + t]; dnb_s[t] = dnb[(size_t)node*NNB + t]; }
  if (t >= 64 && t < 64 + NNB*3) rel_s[t-64] = relnb[(size_t)node*NNB*3 + (t-64)];
  __syncthreads();

  // ---- P1a: fourier features fe[32][9] ----
  if (t < NNB) {
    float d = dnb_s[t];
    float* f = fe_s + t*9;
    f[0] = sinf(d);          f[1] = sinf(d*0.5f);
    f[2] = sinf(d*0.25f);    f[3] = sinf(d*0.125f);
    f[4] = cosf(d);          f[5] = cosf(d*0.5f);
    f[6] = cosf(d*0.25f);    f[7] = cosf(d*0.125f);
    f[8] = d;
  }
  __syncthreads();

  // ---- P1b: ph = relu(fe @ w_p1 + b_p1) -> scr[j][o] ; w_p1,b_p1 global ----
  #pragma unroll
  for (int rep = 0; rep < 8; ++rep) {
    int i2 = t + rep*512;
    int j = i2 >> 7, o = i2 & 127;
    const float* f = fe_s + j*9;
    float acc = b_p1[o];
    #pragma unroll
    for (int r = 0; r < 9; ++r) acc += f[r] * w_p1[r*128 + o];
    scr[j*SCR_LD + o] = fmaxf(acc, 0.0f);
  }
  __syncthreads();

  // ---- P1c: pos = ph @ w_p2 + b_p2 -> pos_s ; w_p2,b_p2 global ----
  {
    int j = t >> 4, og = (t & 15) * 4;
    const float* ph = scr + j*SCR_LD;
    float s0=0,s1=0,s2=0,s3=0, u0=0,u1=0,u2=0,u3=0;
    #pragma unroll 8
    for (int kx = 0; kx < 128; kx += 2) {
      float p0 = ph[kx], p1 = ph[kx+1];
      float4 w0 = *(const float4*)(w_p2 + kx*64 + og);
      float4 w1 = *(const float4*)(w_p2 + (kx+1)*64 + og);
      s0 += p0*w0.x; s1 += p0*w0.y; s2 += p0*w0.z; s3 += p0*w0.w;
      u0 += p1*w1.x; u1 += p1*w1.y; u2 += p1*w1.z; u3 += p1*w1.w;
    }
    float4 bp = *(const float4*)(b_p2 + og);
    pos_s[j*POS_LD+og+0] = bp.x + (s0+u0);
    pos_s[j*POS_LD+og+1] = bp.y + (s1+u1);
    pos_s[j*POS_LD+og+2] = bp.z + (s2+u2);
    pos_s[j*POS_LD+og+3] = bp.w + (s3+u3);
  }
  __syncthreads();

  // ---- P2: pose = pos @ w_e1 -> REGISTERS pr[8] (mapping matches P3 writer) ----
  float pr[8];
  #pragma unroll
  for (int rep = 0; rep < 2; ++rep) {
    int i2 = t + rep*512;
    int j = i2 >> 5, og = (i2 & 31) * 4;
    const float* pj = pos_s + j*POS_LD;
    float s0=0,s1=0,s2=0,s3=0, u0=0,u1=0,u2=0,u3=0;
    #pragma unroll 8
    for (int kx = 0; kx < 64; kx += 2) {
      float p0 = pj[kx], p1 = pj[kx+1];
      float4 w0 = *(const float4*)(w_e1 + kx*128 + og);
      float4 w1 = *(const float4*)(w_e1 + (kx+1)*128 + og);
      s0 += p0*w0.x; s1 += p0*w0.y; s2 += p0*w0.z; s3 += p0*w0.w;
      u0 += p1*w1.x; u1 += p1*w1.y; u2 += p1*w1.z; u3 += p1*w1.w;
    }
    pr[rep*4+0] = s0+u0;
    pr[rep*4+1] = s1+u1;
    pr[rep*4+2] = s2+u2;
    pr[rep*4+3] = s3+u3;
  }
  // no barrier needed: pr is thread-private; scr's last readers were pre-P1c-barrier

  // ---- P3: per head: h1e = relu(qe - ke + pose) ; m = relu(h1e @ w_e2 + b_e2) ----
  for (int h = 0; h < NH; ++h) {
    #pragma unroll
    for (int rep = 0; rep < 2; ++rep) {
      int i2 = t + rep*512;
      int j = i2 >> 5, og = (i2 & 31) * 4;
      float4 kv = *(const float4*)(ke + ((size_t)(((b << 11) + idx_s[j])*NH + h))*128 + og);
      float4 qv = *(const float4*)(qe_s + h*128 + og);
      float4 hv;
      hv.x = fmaxf(qv.x - kv.x + pr[rep*4+0], 0.0f);
      hv.y = fmaxf(qv.y - kv.y + pr[rep*4+1], 0.0f);
      hv.z = fmaxf(qv.z - kv.z + pr[rep*4+2], 0.0f);
      hv.w = fmaxf(qv.w - kv.w + pr[rep*4+3], 0.0f);
      *(float4*)(scr + j*SCR_LD + og) = hv;
    }
    __syncthreads();
    {
      int j = t >> 4, mt = t & 15;
      const float* hp = scr + j*SCR_LD;
      const float* wt = w_e2Ts + mt*E2T_LD;
      float s0=0,s1=0,s2=0,s3=0;
      #pragma unroll 8
      for (int kx = 0; kx < 128; kx += 4) {
        float4 hv = *(const float4*)(hp + kx);
        float4 wv = *(const float4*)(wt + kx);
        s0 += hv.x*wv.x; s1 += hv.y*wv.y; s2 += hv.z*wv.z; s3 += hv.w*wv.w;
      }
      m_all[j*M_LD + h*16 + mt] = fmaxf(b_e2[mt] + ((s0+s1)+(s2+s3)), 0.0f);
    }
    __syncthreads();
  }

  // ---- P4a: sim = relu(m @ w_a1 + b_a1) @ w_a2 + b_a2 ----
  {
    int j = t >> 4, h = (t >> 2) & 3, qq = t & 3;
    float mreg[16];
    #pragma unroll
    for (int mt = 0; mt < 16; ++mt) mreg[mt] = m_all[j*M_LD + h*16 + mt];
    float acc = 0.0f;
    #pragma unroll
    for (int oi = 0; oi < 16; ++oi) {
      int oo = qq*16 + oi;
      float ah = b_a1[oo];
      #pragma unroll
      for (int mt = 0; mt < 16; ++mt) ah += mreg[mt] * w_a1s[mt*64 + oo];
      acc += fmaxf(ah, 0.0f) * w_a2[oo];
    }
    part_s[t] = acc;
  }
  __syncthreads();
  if (t < 128) {
    int j = t >> 2, h = t & 3;
    const float* pp = part_s + j*16 + h*4;
    sim_s[h*32 + j] = ((pp[0]+pp[1]) + (pp[2]+pp[3])) + b_a2[0];
  }
  __syncthreads();
  if (t < 4) {   // softmax over j, faithful to reference
    const float* sp = sim_s + t*32;
    float mx = sp[0];
    for (int j = 1; j < 32; ++j) mx = fmaxf(mx, sp[j]);
    float s = 0.0f; float* ap = attn_s + t*32;
    for (int j = 0; j < 32; ++j) { float e = expf(sp[j] - mx); ap[j] = e; s += e; }
    for (int j = 0; j < 32; ++j) ap[j] = ap[j] / s;
  }
  __syncthreads();

  // ---- P5a: attention output, full width: (jhalf, h, dd) per thread ----
  {
    int jh = t >> 8, h = (t >> 6) & 3, dd = t & 63;
    float acc = 0.0f;
    #pragma unroll
    for (int jj = 0; jj < 16; ++jj) {
      int j = jh*16 + jj;
      float vv = v[(size_t)((b << 11) + idx_s[j])*256 + h*64 + dd] + pos_s[j*POS_LD + dd];
      acc += attn_s[h*32 + j] * vv;
    }
    part_s[t] = acc;
  }
  __syncthreads();
  if (t < 256) hsum[(size_t)node*256 + t] = part_s[t] + part_s[t + 256];
  __syncthreads();

  // ---- P4b: coor MLP: ch = relu(m_all @ w_c1 + b_c1) ; w_c1,b_c1 global ----
  {
    int j = t >> 4, og = (t & 15) * 4;
    const float* mj = m_all + j*M_LD;
    float s0=0,s1=0,s2=0,s3=0, u0=0,u1=0,u2=0,u3=0;
    #pragma unroll 8
    for (int kx = 0; kx < 64; kx += 2) {
      float m0 = mj[kx], m1 = mj[kx+1];
      float4 w0 = *(const float4*)(w_c1 + kx*64 + og);
      float4 w1 = *(const float4*)(w_c1 + (kx+1)*64 + og);
      s0 += m0*w0.x; s1 += m0*w0.y; s2 += m0*w0.z; s3 += m0*w0.w;
      u0 += m1*w1.x; u1 += m1*w1.y; u2 += m1*w1.z; u3 += m1*w1.w;
    }
    float4 bc = *(const float4*)(b_c1 + og);
    scr[j*SCR_LD+og+0] = fmaxf(bc.x + (s0+u0), 0.0f);
    scr[j*SCR_LD+og+1] = fmaxf(bc.y + (s1+u1), 0.0f);
    scr[j*SCR_LD+og+2] = fmaxf(bc.z + (s2+u2), 0.0f);
    scr[j*SCR_LD+og+3] = fmaxf(bc.w + (s3+u3), 0.0f);
  }
  __syncthreads();
  if (t < 128) {
    int j = t >> 2, qq = t & 3;
    const float* cj = scr + j*SCR_LD + qq*16;
    const float* wc = w_c2 + qq*16;
    float acc = 0.0f;
    #pragma unroll
    for (int oo = 0; oo < 16; ++oo) acc += cj[oo] * wc[oo];
    part_s[t] = acc;
  }
  __syncthreads();
  if (t < 32) {
    const float* pp = part_s + t*4;
    cw_s[t] = ((pp[0]+pp[1]) + (pp[2]+pp[3])) + b_c2[0];
  }
  __syncthreads();
  if (t < 3) {
    float acc = 0.0f;
    for (int j = 0; j < 32; ++j) acc += cw_s[j] * rel_s[j*3 + t];
    coors_out[(size_t)node*3 + t] = acc;
  }
}

// ======================= launch =======================
extern "C" void kernel_launch(void* const* d_in, const int* in_sizes, int n_in,
                              void* d_out, int out_size, void* d_ws, size_t ws_size,
                              hipStream_t stream) {
  const float* feats = (const float*)d_in[0];
  const float* coors = (const float*)d_in[1];
  const float* w_qkv = (const float*)d_in[2];
  const float* w_out = (const float*)d_in[3];
  const float* b_out = (const float*)d_in[4];
  const float* w_p1  = (const float*)d_in[5];
  const float* b_p1  = (const float*)d_in[6];
  const float* w_p2  = (const float*)d_in[7];
  const float* b_p2  = (const float*)d_in[8];
  const float* w_e1  = (const float*)d_in[9];
  const float* b_e1  = (const float*)d_in[10];
  const float* w_e2  = (const float*)d_in[11];
  const float* b_e2  = (const float*)d_in[12];
  const float* w_a1  = (const float*)d_in[13];
  const float* b_a1  = (const float*)d_in[14];
  const float* w_a2  = (const float*)d_in[15];
  const float* b_a2  = (const float*)d_in[16];
  const float* w_c1  = (const float*)d_in[17];
  const float* b_c1  = (const float*)d_in[18];
  const float* w_c2  = (const float*)d_in[19];
  const float* b_c2  = (const float*)d_in[20];

  float* ws   = (float*)d_ws;
  float* q    = ws;                 // 4096*256
  float* k    = q   + 1048576;
  float* v    = k   + 1048576;
  float* qe   = v   + 1048576;      // 16384*128 (incl. +b_e1)
  float* ke   = qe  + 2097152;
  float* hsum = ke  + 2097152;      // 4096*256
  int*   idx  = (int*)(hsum + 1048576);   // 4096*32
  float* dnb  = (float*)(idx + 131072);
  float* reln = dnb + 131072;       // 4096*32*3

  float* outF = (float*)d_out;              // (B,N,256)
  float* outC = outF + (size_t)NODES*256;   // (B,N,3)

  knn_kernel<<<dim3(NODES), dim3(256), 0, stream>>>(coors, idx, dnb, reln);

  gemm_kernel<true><<<dim3(64, 12), dim3(256), 0, stream>>>(
      feats, w_qkv, nullptr, q, k, v, 4096, 768, 256, 256, 768);

  gemm_kernel<false><<<dim3(256, 2), dim3(256), 0, stream>>>(
      q, w_e1, b_e1, qe, nullptr, nullptr, 16384, 128, 64, 64, 128);
  gemm_kernel<false><<<dim3(256, 2), dim3(256), 0, stream>>>(
      k, w_e1, nullptr, ke, nullptr, nullptr, 16384, 128, 64, 64, 128);

  constexpr int FUSED_SMEM = 13472 * 4;   // 53,888 B dynamic LDS -> 3 blocks/CU
  (void)hipFuncSetAttribute(reinterpret_cast<const void*>(fused_kernel),
                            hipFuncAttributeMaxDynamicSharedMemorySize, FUSED_SMEM);
  fused_kernel<<<dim3(NODES), dim3(512), FUSED_SMEM, stream>>>(
      idx, dnb, reln, qe, ke, v,
      w_p1, b_p1, w_p2, b_p2, w_e1, w_e2, b_e2,
      w_a1, b_a1, w_a2, b_a2, w_c1, b_c1, w_c2, b_c2,
      hsum, outC);

  gemm_kernel<false><<<dim3(64, 4), dim3(256), 0, stream>>>(
      hsum, w_out, b_out, outF, nullptr, nullptr, 4096, 256, 256, 256, 256);
}

// Round 10
// 727.357 us; speedup vs baseline: 1.1732x; 1.1732x over previous
//
#include <hip/hip_runtime.h>
#include <float.h>
#include <math.h>

#define BB   2
#define NPTS 2048
#define NODES (BB*NPTS)   // 4096
#define NNB  32
#define NH   4
#define NDH  64

// padded LDS row strides (== 4 mod 32 words -> conflict-free broadcast groups)
#define SCR_LD  132
#define POS_LD   68
#define M_LD     68
#define E2T_LD  132

// ======================= KNN (exact numpy replication) =======================
__global__ __launch_bounds__(256) void knn_kernel(const float* __restrict__ coors,
    int* __restrict__ idx_out, float* __restrict__ dnb_out, float* __restrict__ rel_out) {
#pragma clang fp contract(off)
  const int node = blockIdx.x;
  const int b = node >> 11;
  const int i = node & (NPTS - 1);
  __shared__ float cx[NPTS], cy[NPTS], cz[NPTS];
  __shared__ float wdist[4]; __shared__ int wjj[4];
  __shared__ float win_d_s; __shared__ int win_j_s;
  __shared__ float sel_d[NNB]; __shared__ int sel_j[NNB];
  const float* cb = coors + (size_t)b * NPTS * 3;
  for (int j = threadIdx.x; j < NPTS; j += 256) {
    cx[j] = cb[3*j]; cy[j] = cb[3*j+1]; cz[j] = cb[3*j+2];
  }
  __syncthreads();
  const float xi = cx[i], yi = cy[i], zi = cz[i];
  float dl[8]; int jl[8];
  #pragma unroll
  for (int s = 0; s < 8; ++s) {
    int j = threadIdx.x + (s << 8);
    float dx = xi - cx[j];
    float dy = yi - cy[j];
    float dz = zi - cz[j];
    float ss = dx*dx + dy*dy;   // contract(off): matches numpy rounding
    ss = ss + dz*dz;
    dl[s] = sqrtf(ss);          // correctly rounded by default on HIP
    jl[s] = j;
  }
  for (int it = 0; it < NNB; ++it) {
    float bd = FLT_MAX; int bj = 0x7FFFFFFF;
    #pragma unroll
    for (int s = 0; s < 8; ++s)
      if (dl[s] < bd || (dl[s] == bd && jl[s] < bj)) { bd = dl[s]; bj = jl[s]; }
    #pragma unroll
    for (int off = 32; off > 0; off >>= 1) {
      float od = __shfl_down(bd, off, 64);
      int   oj = __shfl_down(bj, off, 64);
      if (od < bd || (od == bd && oj < bj)) { bd = od; bj = oj; }
    }
    if ((threadIdx.x & 63) == 0) { wdist[threadIdx.x >> 6] = bd; wjj[threadIdx.x >> 6] = bj; }
    __syncthreads();
    if (threadIdx.x == 0) {
      float fd = wdist[0]; int fj = wjj[0];
      #pragma unroll
      for (int w = 1; w < 4; ++w)
        if (wdist[w] < fd || (wdist[w] == fd && wjj[w] < fj)) { fd = wdist[w]; fj = wjj[w]; }
      win_d_s = fd; win_j_s = fj; sel_d[it] = fd; sel_j[it] = fj;
    }
    __syncthreads();
    const int wj = win_j_s;
    #pragma unroll
    for (int s = 0; s < 8; ++s) if (jl[s] == wj) dl[s] = FLT_MAX;
    __syncthreads();
  }
  if (threadIdx.x < NNB) {
    int s = threadIdx.x;
    int j = sel_j[s];
    idx_out[(size_t)node*NNB + s] = j;
    dnb_out[(size_t)node*NNB + s] = sel_d[s];
    float* rp = rel_out + ((size_t)node*NNB + s)*3;
    rp[0] = xi - cx[j]; rp[1] = yi - cy[j]; rp[2] = zi - cz[j];
  }
}

// ======================= generic f32 GEMM (64x64 tile) =======================
template<bool SPLIT>
__global__ __launch_bounds__(256) void gemm_kernel(const float* __restrict__ A,
    const float* __restrict__ Bm, const float* __restrict__ bias,
    float* __restrict__ C0, float* __restrict__ C1, float* __restrict__ C2,
    int Mn, int Nn, int Kn, int lda, int ldb) {
  __shared__ float As[64][17];
  __shared__ __align__(16) float Bs[16][64];
  const int bm = blockIdx.x * 64, bn = blockIdx.y * 64;
  const int tx = threadIdx.x & 15, ty = threadIdx.x >> 4;
  const int lm = threadIdx.x >> 2, lk = (threadIdx.x & 3) * 4;
  const int br = threadIdx.x >> 4, bc = (threadIdx.x & 15) * 4;
  float acc[4][4] = {};
  for (int k0 = 0; k0 < Kn; k0 += 16) {
    float4 av = *(const float4*)(A + (size_t)(bm + lm)*lda + k0 + lk);
    As[lm][lk+0] = av.x; As[lm][lk+1] = av.y; As[lm][lk+2] = av.z; As[lm][lk+3] = av.w;
    float4 bv = *(const float4*)(Bm + (size_t)(k0 + br)*ldb + bn + bc);
    *(float4*)&Bs[br][bc] = bv;
    __syncthreads();
    #pragma unroll
    for (int kk = 0; kk < 16; ++kk) {
      float a0 = As[ty*4+0][kk], a1 = As[ty*4+1][kk], a2 = As[ty*4+2][kk], a3 = As[ty*4+3][kk];
      float4 bq = *(const float4*)&Bs[kk][tx*4];
      acc[0][0] += a0*bq.x; acc[0][1] += a0*bq.y; acc[0][2] += a0*bq.z; acc[0][3] += a0*bq.w;
      acc[1][0] += a1*bq.x; acc[1][1] += a1*bq.y; acc[1][2] += a1*bq.z; acc[1][3] += a1*bq.w;
      acc[2][0] += a2*bq.x; acc[2][1] += a2*bq.y; acc[2][2] += a2*bq.z; acc[2][3] += a2*bq.w;
      acc[3][0] += a3*bq.x; acc[3][1] += a3*bq.y; acc[3][2] += a3*bq.z; acc[3][3] += a3*bq.w;
    }
    __syncthreads();
  }
  #pragma unroll
  for (int r = 0; r < 4; ++r) {
    #pragma unroll
    for (int c = 0; c < 4; ++c) {
      int row = bm + ty*4 + r, col = bn + tx*4 + c;
      float vv = acc[r][c];
      if (bias) vv += bias[col];
      if (SPLIT) {
        int w = col >> 8, cc = col & 255;
        float* Cp = (w == 0) ? C0 : ((w == 1) ? C1 : C2);
        Cp[(size_t)row*256 + cc] = vv;
      } else {
        C0[(size_t)row*Nn + col] = vv;
      }
    }
  }
}

// ======================= fused per-node kernel =======================
// block = one node, 512 threads. 53,888 B dynamic LDS.
// pose lives in registers (P2 mapping == P3 consumer mapping).
// launch_bounds(512,4): relaxed VGPR budget -> NO SPILL (R8's (512,6) forced
// VGPR=40 and spilled pr[8] to scratch: WRITE_SIZE 4.3->69.8 MB, +100us).
__global__ __launch_bounds__(512, 4) void fused_kernel(
    const int* __restrict__ idx, const float* __restrict__ dnb, const float* __restrict__ relnb,
    const float* __restrict__ qe, const float* __restrict__ ke, const float* __restrict__ v,
    const float* __restrict__ w_p1, const float* __restrict__ b_p1,
    const float* __restrict__ w_p2, const float* __restrict__ b_p2,
    const float* __restrict__ w_e1, const float* __restrict__ w_e2, const float* __restrict__ b_e2,
    const float* __restrict__ w_a1, const float* __restrict__ b_a1,
    const float* __restrict__ w_a2, const float* __restrict__ b_a2,
    const float* __restrict__ w_c1, const float* __restrict__ b_c1,
    const float* __restrict__ w_c2, const float* __restrict__ b_c2,
    float* __restrict__ hsum, float* __restrict__ coors_out) {
  extern __shared__ float sm[];
  float* w_e2Ts= sm;               // 16*132 = 2112 (transposed)
  float* w_a1s = w_e2Ts + 2112;    // 1024
  float* qe_s  = w_a1s + 1024;     // 512
  float* fe_s  = qe_s + 512;       // 288
  float* pos_s = fe_s + 288;       // 32*68  = 2176
  float* scr   = pos_s + 2176;     // 32*132 = 4224 (ph / h1e / ch)
  float* m_all = scr + 4224;       // 32*68  = 2176
  float* sim_s = m_all + 2176;     // 128
  float* attn_s= sim_s + 128;      // 128
  float* part_s= attn_s + 128;     // 512
  float* cw_s  = part_s + 512;     // 32
  float* dnb_s = cw_s + 32;        // 32
  float* rel_s = dnb_s + 32;       // 96
  int*   idx_s = (int*)(rel_s + 96); // 32  -> total 13472 floats = 53,888 B
  const int t = threadIdx.x;
  const int node = blockIdx.x;
  const int b = node >> 11;

  // ---- stage LDS-resident data ----
  for (int i = t; i < 2048; i += 512) {            // transpose w_e2 [128][16] -> [16][132]
    int kx = i >> 4, mt = i & 15;
    w_e2Ts[mt*E2T_LD + kx] = w_e2[i];
  }
  for (int i = t; i < 1024; i += 512) w_a1s[i] = w_a1[i];
  qe_s[t] = qe[(size_t)node*512 + t];
  if (t < NNB) { idx_s[t] = idx[(size_t)node*NNB + t]; dnb_s[t] = dnb[(size_t)node*NNB + t]; }
  if (t >= 64 && t < 64 + NNB*3) rel_s[t-64] = relnb[(size_t)node*NNB*3 + (t-64)];
  __syncthreads();

  // ---- P1a: fourier features fe[32][9] ----
  if (t < NNB) {
    float d = dnb_s[t];
    float* f = fe_s + t*9;
    f[0] = sinf(d);          f[1] = sinf(d*0.5f);
    f[2] = sinf(d*0.25f);    f[3] = sinf(d*0.125f);
    f[4] = cosf(d);          f[5] = cosf(d*0.5f);
    f[6] = cosf(d*0.25f);    f[7] = cosf(d*0.125f);
    f[8] = d;
  }
  __syncthreads();

  // ---- P1b: ph = relu(fe @ w_p1 + b_p1) -> scr[j][o] ; w_p1,b_p1 global ----
  #pragma unroll
  for (int rep = 0; rep < 8; ++rep) {
    int i2 = t + rep*512;
    int j = i2 >> 7, o = i2 & 127;
    const float* f = fe_s + j*9;
    float acc = b_p1[o];
    #pragma unroll
    for (int r = 0; r < 9; ++r) acc += f[r] * w_p1[r*128 + o];
    scr[j*SCR_LD + o] = fmaxf(acc, 0.0f);
  }
  __syncthreads();

  // ---- P1c: pos = ph @ w_p2 + b_p2 -> pos_s ; w_p2,b_p2 global ----
  {
    int j = t >> 4, og = (t & 15) * 4;
    const float* ph = scr + j*SCR_LD;
    float s0=0,s1=0,s2=0,s3=0, u0=0,u1=0,u2=0,u3=0;
    #pragma unroll 8
    for (int kx = 0; kx < 128; kx += 2) {
      float p0 = ph[kx], p1 = ph[kx+1];
      float4 w0 = *(const float4*)(w_p2 + kx*64 + og);
      float4 w1 = *(const float4*)(w_p2 + (kx+1)*64 + og);
      s0 += p0*w0.x; s1 += p0*w0.y; s2 += p0*w0.z; s3 += p0*w0.w;
      u0 += p1*w1.x; u1 += p1*w1.y; u2 += p1*w1.z; u3 += p1*w1.w;
    }
    float4 bp = *(const float4*)(b_p2 + og);
    pos_s[j*POS_LD+og+0] = bp.x + (s0+u0);
    pos_s[j*POS_LD+og+1] = bp.y + (s1+u1);
    pos_s[j*POS_LD+og+2] = bp.z + (s2+u2);
    pos_s[j*POS_LD+og+3] = bp.w + (s3+u3);
  }
  __syncthreads();

  // ---- P2: pose = pos @ w_e1 -> REGISTERS pr[8] (mapping matches P3 writer) ----
  float pr[8];
  #pragma unroll
  for (int rep = 0; rep < 2; ++rep) {
    int i2 = t + rep*512;
    int j = i2 >> 5, og = (i2 & 31) * 4;
    const float* pj = pos_s + j*POS_LD;
    float s0=0,s1=0,s2=0,s3=0, u0=0,u1=0,u2=0,u3=0;
    #pragma unroll 8
    for (int kx = 0; kx < 64; kx += 2) {
      float p0 = pj[kx], p1 = pj[kx+1];
      float4 w0 = *(const float4*)(w_e1 + kx*128 + og);
      float4 w1 = *(const float4*)(w_e1 + (kx+1)*128 + og);
      s0 += p0*w0.x; s1 += p0*w0.y; s2 += p0*w0.z; s3 += p0*w0.w;
      u0 += p1*w1.x; u1 += p1*w1.y; u2 += p1*w1.z; u3 += p1*w1.w;
    }
    pr[rep*4+0] = s0+u0;
    pr[rep*4+1] = s1+u1;
    pr[rep*4+2] = s2+u2;
    pr[rep*4+3] = s3+u3;
  }
  // no barrier needed: pr is thread-private; scr's last readers were pre-P1c-barrier

  // ---- P3: per head: h1e = relu(qe - ke + pose) ; m = relu(h1e @ w_e2 + b_e2) ----
  for (int h = 0; h < NH; ++h) {
    #pragma unroll
    for (int rep = 0; rep < 2; ++rep) {
      int i2 = t + rep*512;
      int j = i2 >> 5, og = (i2 & 31) * 4;
      float4 kv = *(const float4*)(ke + ((size_t)(((b << 11) + idx_s[j])*NH + h))*128 + og);
      float4 qv = *(const float4*)(qe_s + h*128 + og);
      float4 hv;
      hv.x = fmaxf(qv.x - kv.x + pr[rep*4+0], 0.0f);
      hv.y = fmaxf(qv.y - kv.y + pr[rep*4+1], 0.0f);
      hv.z = fmaxf(qv.z - kv.z + pr[rep*4+2], 0.0f);
      hv.w = fmaxf(qv.w - kv.w + pr[rep*4+3], 0.0f);
      *(float4*)(scr + j*SCR_LD + og) = hv;
    }
    __syncthreads();
    {
      int j = t >> 4, mt = t & 15;
      const float* hp = scr + j*SCR_LD;
      const float* wt = w_e2Ts + mt*E2T_LD;
      float s0=0,s1=0,s2=0,s3=0;
      #pragma unroll 8
      for (int kx = 0; kx < 128; kx += 4) {
        float4 hv = *(const float4*)(hp + kx);
        float4 wv = *(const float4*)(wt + kx);
        s0 += hv.x*wv.x; s1 += hv.y*wv.y; s2 += hv.z*wv.z; s3 += hv.w*wv.w;
      }
      m_all[j*M_LD + h*16 + mt] = fmaxf(b_e2[mt] + ((s0+s1)+(s2+s3)), 0.0f);
    }
    __syncthreads();
  }

  // ---- P4a: sim = relu(m @ w_a1 + b_a1) @ w_a2 + b_a2 ----
  {
    int j = t >> 4, h = (t >> 2) & 3, qq = t & 3;
    float mreg[16];
    #pragma unroll
    for (int mt = 0; mt < 16; ++mt) mreg[mt] = m_all[j*M_LD + h*16 + mt];
    float acc = 0.0f;
    #pragma unroll
    for (int oi = 0; oi < 16; ++oi) {
      int oo = qq*16 + oi;
      float ah = b_a1[oo];
      #pragma unroll
      for (int mt = 0; mt < 16; ++mt) ah += mreg[mt] * w_a1s[mt*64 + oo];
      acc += fmaxf(ah, 0.0f) * w_a2[oo];
    }
    part_s[t] = acc;
  }
  __syncthreads();
  if (t < 128) {
    int j = t >> 2, h = t & 3;
    const float* pp = part_s + j*16 + h*4;
    sim_s[h*32 + j] = ((pp[0]+pp[1]) + (pp[2]+pp[3])) + b_a2[0];
  }
  __syncthreads();
  if (t < 4) {   // softmax over j, faithful to reference
    const float* sp = sim_s + t*32;
    float mx = sp[0];
    for (int j = 1; j < 32; ++j) mx = fmaxf(mx, sp[j]);
    float s = 0.0f; float* ap = attn_s + t*32;
    for (int j = 0; j < 32; ++j) { float e = expf(sp[j] - mx); ap[j] = e; s += e; }
    for (int j = 0; j < 32; ++j) ap[j] = ap[j] / s;
  }
  __syncthreads();

  // ---- P5a: attention output, full width: (jhalf, h, dd) per thread ----
  {
    int jh = t >> 8, h = (t >> 6) & 3, dd = t & 63;
    float acc = 0.0f;
    #pragma unroll
    for (int jj = 0; jj < 16; ++jj) {
      int j = jh*16 + jj;
      float vv = v[(size_t)((b << 11) + idx_s[j])*256 + h*64 + dd] + pos_s[j*POS_LD + dd];
      acc += attn_s[h*32 + j] * vv;
    }
    part_s[t] = acc;
  }
  __syncthreads();
  if (t < 256) hsum[(size_t)node*256 + t] = part_s[t] + part_s[t + 256];
  __syncthreads();

  // ---- P4b: coor MLP: ch = relu(m_all @ w_c1 + b_c1) ; w_c1,b_c1 global ----
  {
    int j = t >> 4, og = (t & 15) * 4;
    const float* mj = m_all + j*M_LD;
    float s0=0,s1=0,s2=0,s3=0, u0=0,u1=0,u2=0,u3=0;
    #pragma unroll 8
    for (int kx = 0; kx < 64; kx += 2) {
      float m0 = mj[kx], m1 = mj[kx+1];
      float4 w0 = *(const float4*)(w_c1 + kx*64 + og);
      float4 w1 = *(const float4*)(w_c1 + (kx+1)*64 + og);
      s0 += m0*w0.x; s1 += m0*w0.y; s2 += m0*w0.z; s3 += m0*w0.w;
      u0 += m1*w1.x; u1 += m1*w1.y; u2 += m1*w1.z; u3 += m1*w1.w;
    }
    float4 bc = *(const float4*)(b_c1 + og);
    scr[j*SCR_LD+og+0] = fmaxf(bc.x + (s0+u0), 0.0f);
    scr[j*SCR_LD+og+1] = fmaxf(bc.y + (s1+u1), 0.0f);
    scr[j*SCR_LD+og+2] = fmaxf(bc.z + (s2+u2), 0.0f);
    scr[j*SCR_LD+og+3] = fmaxf(bc.w + (s3+u3), 0.0f);
  }
  __syncthreads();
  if (t < 128) {
    int j = t >> 2, qq = t & 3;
    const float* cj = scr + j*SCR_LD + qq*16;
    const float* wc = w_c2 + qq*16;
    float acc = 0.0f;
    #pragma unroll
    for (int oo = 0; oo < 16; ++oo) acc += cj[oo] * wc[oo];
    part_s[t] = acc;
  }
  __syncthreads();
  if (t < 32) {
    const float* pp = part_s + t*4;
    cw_s[t] = ((pp[0]+pp[1]) + (pp[2]+pp[3])) + b_c2[0];
  }
  __syncthreads();
  if (t < 3) {
    float acc = 0.0f;
    for (int j = 0; j < 32; ++j) acc += cw_s[j] * rel_s[j*3 + t];
    coors_out[(size_t)node*3 + t] = acc;
  }
}

// ======================= launch =======================
extern "C" void kernel_launch(void* const* d_in, const int* in_sizes, int n_in,
                              void* d_out, int out_size, void* d_ws, size_t ws_size,
                              hipStream_t stream) {
  const float* feats = (const float*)d_in[0];
  const float* coors = (const float*)d_in[1];
  const float* w_qkv = (const float*)d_in[2];
  const float* w_out = (const float*)d_in[3];
  const float* b_out = (const float*)d_in[4];
  const float* w_p1  = (const float*)d_in[5];
  const float* b_p1  = (const float*)d_in[6];
  const float* w_p2  = (const float*)d_in[7];
  const float* b_p2  = (const float*)d_in[8];
  const float* w_e1  = (const float*)d_in[9];
  const float* b_e1  = (const float*)d_in[10];
  const float* w_e2  = (const float*)d_in[11];
  const float* b_e2  = (const float*)d_in[12];
  const float* w_a1  = (const float*)d_in[13];
  const float* b_a1  = (const float*)d_in[14];
  const float* w_a2  = (const float*)d_in[15];
  const float* b_a2  = (const float*)d_in[16];
  const float* w_c1  = (const float*)d_in[17];
  const float* b_c1  = (const float*)d_in[18];
  const float* w_c2  = (const float*)d_in[19];
  const float* b_c2  = (const float*)d_in[20];

  float* ws   = (float*)d_ws;
  float* q    = ws;                 // 4096*256
  float* k    = q   + 1048576;
  float* v    = k   + 1048576;
  float* qe   = v   + 1048576;      // 16384*128 (incl. +b_e1)
  float* ke   = qe  + 2097152;
  float* hsum = ke  + 2097152;      // 4096*256
  int*   idx  = (int*)(hsum + 1048576);   // 4096*32
  float* dnb  = (float*)(idx + 131072);
  float* reln = dnb + 131072;       // 4096*32*3

  float* outF = (float*)d_out;              // (B,N,256)
  float* outC = outF + (size_t)NODES*256;   // (B,N,3)

  knn_kernel<<<dim3(NODES), dim3(256), 0, stream>>>(coors, idx, dnb, reln);

  gemm_kernel<true><<<dim3(64, 12), dim3(256), 0, stream>>>(
      feats, w_qkv, nullptr, q, k, v, 4096, 768, 256, 256, 768);

  gemm_kernel<false><<<dim3(256, 2), dim3(256), 0, stream>>>(
      q, w_e1, b_e1, qe, nullptr, nullptr, 16384, 128, 64, 64, 128);
  gemm_kernel<false><<<dim3(256, 2), dim3(256), 0, stream>>>(
      k, w_e1, nullptr, ke, nullptr, nullptr, 16384, 128, 64, 64, 128);

  constexpr int FUSED_SMEM = 13472 * 4;   // 53,888 B dynamic LDS
  (void)hipFuncSetAttribute(reinterpret_cast<const void*>(fused_kernel),
                            hipFuncAttributeMaxDynamicSharedMemorySize, FUSED_SMEM);
  fused_kernel<<<dim3(NODES), dim3(512), FUSED_SMEM, stream>>>(
      idx, dnb, reln, qe, ke, v,
      w_p1, b_p1, w_p2, b_p2, w_e1, w_e2, b_e2,
      w_a1, b_a1, w_a2, b_a2, w_c1, b_c1, w_c2, b_c2,
      hsum, outC);

  gemm_kernel<false><<<dim3(64, 4), dim3(256), 0, stream>>>(
      hsum, w_out, b_out, outF, nullptr, nullptr, 4096, 256, 256, 256, 256);
}

// Round 14
// 684.852 us; speedup vs baseline: 1.2460x; 1.0621x over previous
//
#include <hip/hip_runtime.h>
#include <float.h>
#include <math.h>

#define BB   2
#define NPTS 2048
#define NODES (BB*NPTS)   // 4096
#define NNB  32
#define NH   4
#define NDH  64

// padded LDS row strides (== 4 mod 32 words -> conflict-free broadcast groups)
#define SCR_LD  132
#define POS_LD   68
#define M_LD     68
#define E2T_LD  132

// ======================= KNN (exact numpy replication) =======================
__global__ __launch_bounds__(256) void knn_kernel(const float* __restrict__ coors,
    int* __restrict__ idx_out, float* __restrict__ dnb_out, float* __restrict__ rel_out) {
#pragma clang fp contract(off)
  const int node = blockIdx.x;
  const int b = node >> 11;
  const int i = node & (NPTS - 1);
  __shared__ float cx[NPTS], cy[NPTS], cz[NPTS];
  __shared__ float wdist[4]; __shared__ int wjj[4];
  __shared__ float win_d_s; __shared__ int win_j_s;
  __shared__ float sel_d[NNB]; __shared__ int sel_j[NNB];
  const float* cb = coors + (size_t)b * NPTS * 3;
  for (int j = threadIdx.x; j < NPTS; j += 256) {
    cx[j] = cb[3*j]; cy[j] = cb[3*j+1]; cz[j] = cb[3*j+2];
  }
  __syncthreads();
  const float xi = cx[i], yi = cy[i], zi = cz[i];
  float dl[8]; int jl[8];
  #pragma unroll
  for (int s = 0; s < 8; ++s) {
    int j = threadIdx.x + (s << 8);
    float dx = xi - cx[j];
    float dy = yi - cy[j];
    float dz = zi - cz[j];
    float ss = dx*dx + dy*dy;   // contract(off): matches numpy rounding
    ss = ss + dz*dz;
    dl[s] = sqrtf(ss);          // correctly rounded by default on HIP
    jl[s] = j;
  }
  for (int it = 0; it < NNB; ++it) {
    float bd = FLT_MAX; int bj = 0x7FFFFFFF;
    #pragma unroll
    for (int s = 0; s < 8; ++s)
      if (dl[s] < bd || (dl[s] == bd && jl[s] < bj)) { bd = dl[s]; bj = jl[s]; }
    #pragma unroll
    for (int off = 32; off > 0; off >>= 1) {
      float od = __shfl_down(bd, off, 64);
      int   oj = __shfl_down(bj, off, 64);
      if (od < bd || (od == bd && oj < bj)) { bd = od; bj = oj; }
    }
    if ((threadIdx.x & 63) == 0) { wdist[threadIdx.x >> 6] = bd; wjj[threadIdx.x >> 6] = bj; }
    __syncthreads();
    if (threadIdx.x == 0) {
      float fd = wdist[0]; int fj = wjj[0];
      #pragma unroll
      for (int w = 1; w < 4; ++w)
        if (wdist[w] < fd || (wdist[w] == fd && wjj[w] < fj)) { fd = wdist[w]; fj = wjj[w]; }
      win_d_s = fd; win_j_s = fj; sel_d[it] = fd; sel_j[it] = fj;
    }
    __syncthreads();
    const int wj = win_j_s;
    #pragma unroll
    for (int s = 0; s < 8; ++s) if (jl[s] == wj) dl[s] = FLT_MAX;
    __syncthreads();
  }
  if (threadIdx.x < NNB) {
    int s = threadIdx.x;
    int j = sel_j[s];
    idx_out[(size_t)node*NNB + s] = j;
    dnb_out[(size_t)node*NNB + s] = sel_d[s];
    float* rp = rel_out + ((size_t)node*NNB + s)*3;
    rp[0] = xi - cx[j]; rp[1] = yi - cy[j]; rp[2] = zi - cz[j];
  }
}

// ======================= generic f32 GEMM (64x64 tile) =======================
template<bool SPLIT>
__global__ __launch_bounds__(256) void gemm_kernel(const float* __restrict__ A,
    const float* __restrict__ Bm, const float* __restrict__ bias,
    float* __restrict__ C0, float* __restrict__ C1, float* __restrict__ C2,
    int Mn, int Nn, int Kn, int lda, int ldb) {
  __shared__ float As[64][17];
  __shared__ __align__(16) float Bs[16][64];
  const int bm = blockIdx.x * 64, bn = blockIdx.y * 64;
  const int tx = threadIdx.x & 15, ty = threadIdx.x >> 4;
  const int lm = threadIdx.x >> 2, lk = (threadIdx.x & 3) * 4;
  const int br = threadIdx.x >> 4, bc = (threadIdx.x & 15) * 4;
  float acc[4][4] = {};
  for (int k0 = 0; k0 < Kn; k0 += 16) {
    float4 av = *(const float4*)(A + (size_t)(bm + lm)*lda + k0 + lk);
    As[lm][lk+0] = av.x; As[lm][lk+1] = av.y; As[lm][lk+2] = av.z; As[lm][lk+3] = av.w;
    float4 bv = *(const float4*)(Bm + (size_t)(k0 + br)*ldb + bn + bc);
    *(float4*)&Bs[br][bc] = bv;
    __syncthreads();
    #pragma unroll
    for (int kk = 0; kk < 16; ++kk) {
      float a0 = As[ty*4+0][kk], a1 = As[ty*4+1][kk], a2 = As[ty*4+2][kk], a3 = As[ty*4+3][kk];
      float4 bq = *(const float4*)&Bs[kk][tx*4];
      acc[0][0] += a0*bq.x; acc[0][1] += a0*bq.y; acc[0][2] += a0*bq.z; acc[0][3] += a0*bq.w;
      acc[1][0] += a1*bq.x; acc[1][1] += a1*bq.y; acc[1][2] += a1*bq.z; acc[1][3] += a1*bq.w;
      acc[2][0] += a2*bq.x; acc[2][1] += a2*bq.y; acc[2][2] += a2*bq.z; acc[2][3] += a2*bq.w;
      acc[3][0] += a3*bq.x; acc[3][1] += a3*bq.y; acc[3][2] += a3*bq.z; acc[3][3] += a3*bq.w;
    }
    __syncthreads();
  }
  #pragma unroll
  for (int r = 0; r < 4; ++r) {
    #pragma unroll
    for (int c = 0; c < 4; ++c) {
      int row = bm + ty*4 + r, col = bn + tx*4 + c;
      float vv = acc[r][c];
      if (bias) vv += bias[col];
      if (SPLIT) {
        int w = col >> 8, cc = col & 255;
        float* Cp = (w == 0) ? C0 : ((w == 1) ? C1 : C2);
        Cp[(size_t)row*256 + cc] = vv;
      } else {
        C0[(size_t)row*Nn + col] = vv;
      }
    }
  }
}

// ======================= fused per-node kernel =======================
// block = one node, 512 threads = 8 waves. 53,888 B dynamic LDS.
// WAVE-OWNS-NEIGHBORS: wave w handles j = 4w..4w+3 through P1a..P4b with NO
// block barriers (intra-wave LDS deps only; CDNA waves are lockstep and LDS
// ops are program-ordered per wave). Only 4 __syncthreads() total.
__global__ __launch_bounds__(512, 4) void fused_kernel(
    const int* __restrict__ idx, const float* __restrict__ dnb, const float* __restrict__ relnb,
    const float* __restrict__ qe, const float* __restrict__ ke, const float* __restrict__ v,
    const float* __restrict__ w_p1, const float* __restrict__ b_p1,
    const float* __restrict__ w_p2, const float* __restrict__ b_p2,
    const float* __restrict__ w_e1, const float* __restrict__ w_e2, const float* __restrict__ b_e2,
    const float* __restrict__ w_a1, const float* __restrict__ b_a1,
    const float* __restrict__ w_a2, const float* __restrict__ b_a2,
    const float* __restrict__ w_c1, const float* __restrict__ b_c1,
    const float* __restrict__ w_c2, const float* __restrict__ b_c2,
    float* __restrict__ hsum, float* __restrict__ coors_out) {
  extern __shared__ float sm[];
  float* w_e2Ts= sm;               // 16*132 = 2112 (transposed)
  float* w_a1s = w_e2Ts + 2112;    // 1024
  float* qe_s  = w_a1s + 1024;     // 512
  float* fe_s  = qe_s + 512;       // 288
  float* pos_s = fe_s + 288;       // 32*68  = 2176
  float* scr   = pos_s + 2176;     // 32*132 = 4224 (ph / h1e per-wave rows)
  float* m_all = scr + 4224;       // 32*68  = 2176
  float* sim_s = m_all + 2176;     // 128
  float* attn_s= sim_s + 128;      // 128
  float* part_s= attn_s + 128;     // 512
  float* cw_s  = part_s + 512;     // 32
  float* dnb_s = cw_s + 32;        // 32
  float* rel_s = dnb_s + 32;       // 96
  int*   idx_s = (int*)(rel_s + 96); // 32  -> total 13472 floats = 53,888 B
  const int t = threadIdx.x;
  const int node = blockIdx.x;
  const int b = node >> 11;
  const int w   = t >> 6;          // wave 0..7
  const int l   = t & 63;          // lane 0..63
  const int jw  = (w << 2) | (l >> 4);   // this lane's neighbor row (4 per wave)
  const int l16 = l & 15;

  // ---- stage LDS-resident data ----
  for (int i = t; i < 2048; i += 512) {            // transpose w_e2 [128][16] -> [16][132]
    int kx = i >> 4, mt = i & 15;
    w_e2Ts[mt*E2T_LD + kx] = w_e2[i];
  }
  for (int i = t; i < 1024; i += 512) w_a1s[i] = w_a1[i];
  qe_s[t] = qe[(size_t)node*512 + t];
  if (t < NNB) { idx_s[t] = idx[(size_t)node*NNB + t]; dnb_s[t] = dnb[(size_t)node*NNB + t]; }
  if (t >= 64 && t < 64 + NNB*3) rel_s[t-64] = relnb[(size_t)node*NNB*3 + (t-64)];
  __syncthreads();   // B1: staged weights/qe/idx/dnb/rel visible to all waves

  // ---- P1a: fourier features, lanes 0..3 of each wave do own rows ----
  if (l < 4) {
    int jj = (w << 2) | l;
    float d = dnb_s[jj];
    float* f = fe_s + jj*9;
    f[0] = sinf(d);          f[1] = sinf(d*0.5f);
    f[2] = sinf(d*0.25f);    f[3] = sinf(d*0.125f);
    f[4] = cosf(d);          f[5] = cosf(d*0.5f);
    f[6] = cosf(d*0.25f);    f[7] = cosf(d*0.125f);
    f[8] = d;
  }
  // in-wave dep: fe_s rows 4w..4w+3 read below by same wave only

  // ---- P1b: ph = relu(fe @ w_p1 + b_p1) -> scr[jw][o8..o8+7] ----
  {
    const int o8 = l16*8;
    float4 a0 = *(const float4*)(b_p1 + o8);
    float4 a1 = *(const float4*)(b_p1 + o8 + 4);
    #pragma unroll
    for (int r = 0; r < 9; ++r) {
      float fr = fe_s[jw*9 + r];
      float4 w0 = *(const float4*)(w_p1 + r*128 + o8);
      float4 w1 = *(const float4*)(w_p1 + r*128 + o8 + 4);
      a0.x += fr*w0.x; a0.y += fr*w0.y; a0.z += fr*w0.z; a0.w += fr*w0.w;
      a1.x += fr*w1.x; a1.y += fr*w1.y; a1.z += fr*w1.z; a1.w += fr*w1.w;
    }
    a0.x = fmaxf(a0.x,0.f); a0.y = fmaxf(a0.y,0.f); a0.z = fmaxf(a0.z,0.f); a0.w = fmaxf(a0.w,0.f);
    a1.x = fmaxf(a1.x,0.f); a1.y = fmaxf(a1.y,0.f); a1.z = fmaxf(a1.z,0.f); a1.w = fmaxf(a1.w,0.f);
    *(float4*)(scr + jw*SCR_LD + o8)     = a0;
    *(float4*)(scr + jw*SCR_LD + o8 + 4) = a1;
  }

  // ---- P1c: pos = ph @ w_p2 + b_p2 -> pos_s[jw][og..og+3] ----
  {
    const int og = l16*4;
    const float* ph = scr + jw*SCR_LD;
    float s0=0,s1=0,s2=0,s3=0;
    #pragma unroll 8
    for (int kx = 0; kx < 128; ++kx) {
      float p = ph[kx];
      float4 wv = *(const float4*)(w_p2 + kx*64 + og);
      s0 += p*wv.x; s1 += p*wv.y; s2 += p*wv.z; s3 += p*wv.w;
    }
    float4 bp = *(const float4*)(b_p2 + og);
    pos_s[jw*POS_LD+og+0] = bp.x + s0;
    pos_s[jw*POS_LD+og+1] = bp.y + s1;
    pos_s[jw*POS_LD+og+2] = bp.z + s2;
    pos_s[jw*POS_LD+og+3] = bp.w + s3;
  }

  // ---- P2: pose = pos @ w_e1 -> registers pr[8] (o = l16*8 .. +7) ----
  float pr[8];
  {
    const int o8 = l16*8;
    const float* pj = pos_s + jw*POS_LD;
    float s0=0,s1=0,s2=0,s3=0,s4=0,s5=0,s6=0,s7=0;
    #pragma unroll 8
    for (int kx = 0; kx < 64; ++kx) {
      float p = pj[kx];
      float4 w0 = *(const float4*)(w_e1 + kx*128 + o8);
      float4 w1 = *(const float4*)(w_e1 + kx*128 + o8 + 4);
      s0 += p*w0.x; s1 += p*w0.y; s2 += p*w0.z; s3 += p*w0.w;
      s4 += p*w1.x; s5 += p*w1.y; s6 += p*w1.z; s7 += p*w1.w;
    }
    pr[0]=s0; pr[1]=s1; pr[2]=s2; pr[3]=s3; pr[4]=s4; pr[5]=s5; pr[6]=s6; pr[7]=s7;
  }

  // ---- P3: per head: h1e = relu(qe - ke + pose) -> scr[jw]; GEMV -> m_all ----
  {
    const size_t kebase = ((size_t)((b << 11) + idx_s[jw])*NH)*128;
    const int o8 = l16*8;
    for (int h = 0; h < NH; ++h) {
      float4 kv0 = *(const float4*)(ke + kebase + h*128 + o8);
      float4 kv1 = *(const float4*)(ke + kebase + h*128 + o8 + 4);
      float4 qv0 = *(const float4*)(qe_s + h*128 + o8);
      float4 qv1 = *(const float4*)(qe_s + h*128 + o8 + 4);
      float4 h0, h1;
      h0.x = fmaxf(qv0.x - kv0.x + pr[0], 0.f);
      h0.y = fmaxf(qv0.y - kv0.y + pr[1], 0.f);
      h0.z = fmaxf(qv0.z - kv0.z + pr[2], 0.f);
      h0.w = fmaxf(qv0.w - kv0.w + pr[3], 0.f);
      h1.x = fmaxf(qv1.x - kv1.x + pr[4], 0.f);
      h1.y = fmaxf(qv1.y - kv1.y + pr[5], 0.f);
      h1.z = fmaxf(qv1.z - kv1.z + pr[6], 0.f);
      h1.w = fmaxf(qv1.w - kv1.w + pr[7], 0.f);
      *(float4*)(scr + jw*SCR_LD + o8)     = h0;
      *(float4*)(scr + jw*SCR_LD + o8 + 4) = h1;
      // GEMV: one output (jw, mt=l16); in-wave dep on scr row jw
      const float* hp = scr + jw*SCR_LD;
      const float* wt = w_e2Ts + l16*E2T_LD;
      float s0=0,s1=0,s2=0,s3=0;
      #pragma unroll 8
      for (int kx = 0; kx < 128; kx += 4) {
        float4 hv = *(const float4*)(hp + kx);
        float4 wv = *(const float4*)(wt + kx);
        s0 += hv.x*wv.x; s1 += hv.y*wv.y; s2 += hv.z*wv.z; s3 += hv.w*wv.w;
      }
      m_all[jw*M_LD + h*16 + l16] = fmaxf(b_e2[l16] + ((s0+s1)+(s2+s3)), 0.0f);
    }
  }

  // ---- P4a: sim, wave-local: lane = (jl, h, qq); shfl-reduce over qq ----
  {
    const int jj = (w << 2) | (l >> 4);
    const int hh = (l >> 2) & 3, qq = l & 3;
    float mreg[16];
    #pragma unroll
    for (int mt = 0; mt < 16; ++mt) mreg[mt] = m_all[jj*M_LD + hh*16 + mt];
    float acc = 0.0f;
    #pragma unroll
    for (int oi = 0; oi < 16; ++oi) {
      int oo = qq*16 + oi;
      float ah = b_a1[oo];
      #pragma unroll
      for (int mt = 0; mt < 16; ++mt) ah += mreg[mt] * w_a1s[mt*64 + oo];
      acc += fmaxf(ah, 0.0f) * w_a2[oo];
    }
    acc += __shfl_down(acc, 2, 4);
    acc += __shfl_down(acc, 1, 4);
    if (qq == 0) sim_s[hh*32 + jj] = acc + b_a2[0];
  }

  // ---- P4b: coor MLP wave-local: ch in regs, cw via shfl-reduce ----
  {
    const int og = l16*4;
    const float* mj = m_all + jw*M_LD;
    float s0=0,s1=0,s2=0,s3=0;
    #pragma unroll 8
    for (int kx = 0; kx < 64; ++kx) {
      float m0 = mj[kx];
      float4 wv = *(const float4*)(w_c1 + kx*64 + og);
      s0 += m0*wv.x; s1 += m0*wv.y; s2 += m0*wv.z; s3 += m0*wv.w;
    }
    float4 bc = *(const float4*)(b_c1 + og);
    float c0 = fmaxf(bc.x + s0, 0.f), c1 = fmaxf(bc.y + s1, 0.f);
    float c2 = fmaxf(bc.z + s2, 0.f), c3 = fmaxf(bc.w + s3, 0.f);
    float4 wc = *(const float4*)(w_c2 + og);
    float part = ((c0*wc.x + c1*wc.y) + (c2*wc.z + c3*wc.w));
    part += __shfl_down(part, 8, 16);
    part += __shfl_down(part, 4, 16);
    part += __shfl_down(part, 2, 16);
    part += __shfl_down(part, 1, 16);
    if (l16 == 0) cw_s[jw] = part + b_c2[0];
  }
  __syncthreads();   // B2: sim_s, cw_s, pos_s (all rows) now visible block-wide

  // ---- coors_out (lanes 64..66) and softmax (lanes 0..3), concurrent ----
  if (t >= 64 && t < 67) {
    int c = t - 64;
    float acc = 0.0f;
    for (int j = 0; j < 32; ++j) acc += cw_s[j] * rel_s[j*3 + c];
    coors_out[(size_t)node*3 + c] = acc;
  }
  if (t < 4) {   // softmax over j, faithful to reference
    const float* sp = sim_s + t*32;
    float mx = sp[0];
    for (int j = 1; j < 32; ++j) mx = fmaxf(mx, sp[j]);
    float s = 0.0f; float* ap = attn_s + t*32;
    for (int j = 0; j < 32; ++j) { float e = expf(sp[j] - mx); ap[j] = e; s += e; }
    for (int j = 0; j < 32; ++j) ap[j] = ap[j] / s;
  }
  __syncthreads();   // B3: attn_s visible

  // ---- P5a: attention output, full width: (jhalf, h, dd) per thread ----
  {
    int jh = t >> 8, h = (t >> 6) & 3, dd = t & 63;
    float acc = 0.0f;
    #pragma unroll
    for (int jj = 0; jj < 16; ++jj) {
      int j = jh*16 + jj;
      float vv = v[(size_t)((b << 11) + idx_s[j])*256 + h*64 + dd] + pos_s[j*POS_LD + dd];
      acc += attn_s[h*32 + j] * vv;
    }
    part_s[t] = acc;
  }
  __syncthreads();   // B4
  if (t < 256) hsum[(size_t)node*256 + t] = part_s[t] + part_s[t + 256];
}

// ======================= launch =======================
extern "C" void kernel_launch(void* const* d_in, const int* in_sizes, int n_in,
                              void* d_out, int out_size, void* d_ws, size_t ws_size,
                              hipStream_t stream) {
  const float* feats = (const float*)d_in[0];
  const float* coors = (const float*)d_in[1];
  const float* w_qkv = (const float*)d_in[2];
  const float* w_out = (const float*)d_in[3];
  const float* b_out = (const float*)d_in[4];
  const float* w_p1  = (const float*)d_in[5];
  const float* b_p1  = (const float*)d_in[6];
  const float* w_p2  = (const float*)d_in[7];
  const float* b_p2  = (const float*)d_in[8];
  const float* w_e1  = (const float*)d_in[9];
  const float* b_e1  = (const float*)d_in[10];
  const float* w_e2  = (const float*)d_in[11];
  const float* b_e2  = (const float*)d_in[12];
  const float* w_a1  = (const float*)d_in[13];
  const float* b_a1  = (const float*)d_in[14];
  const float* w_a2  = (const float*)d_in[15];
  const float* b_a2  = (const float*)d_in[16];
  const float* w_c1  = (const float*)d_in[17];
  const float* b_c1  = (const float*)d_in[18];
  const float* w_c2  = (const float*)d_in[19];
  const float* b_c2  = (const float*)d_in[20];

  float* ws   = (float*)d_ws;
  float* q    = ws;                 // 4096*256
  float* k    = q   + 1048576;
  float* v    = k   + 1048576;
  float* qe   = v   + 1048576;      // 16384*128 (incl. +b_e1)
  float* ke   = qe  + 2097152;
  float* hsum = ke  + 2097152;      // 4096*256
  int*   idx  = (int*)(hsum + 1048576);   // 4096*32
  float* dnb  = (float*)(idx + 131072);
  float* reln = dnb + 131072;       // 4096*32*3

  float* outF = (float*)d_out;              // (B,N,256)
  float* outC = outF + (size_t)NODES*256;   // (B,N,3)

  knn_kernel<<<dim3(NODES), dim3(256), 0, stream>>>(coors, idx, dnb, reln);

  gemm_kernel<true><<<dim3(64, 12), dim3(256), 0, stream>>>(
      feats, w_qkv, nullptr, q, k, v, 4096, 768, 256, 256, 768);

  gemm_kernel<false><<<dim3(256, 2), dim3(256), 0, stream>>>(
      q, w_e1, b_e1, qe, nullptr, nullptr, 16384, 128, 64, 64, 128);
  gemm_kernel<false><<<dim3(256, 2), dim3(256), 0, stream>>>(
      k, w_e1, nullptr, ke, nullptr, nullptr, 16384, 128, 64, 64, 128);

  constexpr int FUSED_SMEM = 13472 * 4;   // 53,888 B dynamic LDS
  (void)hipFuncSetAttribute(reinterpret_cast<const void*>(fused_kernel),
                            hipFuncAttributeMaxDynamicSharedMemorySize, FUSED_SMEM);
  fused_kernel<<<dim3(NODES), dim3(512), FUSED_SMEM, stream>>>(
      idx, dnb, reln, qe, ke, v,
      w_p1, b_p1, w_p2, b_p2, w_e1, w_e2, b_e2,
      w_a1, b_a1, w_a2, b_a2, w_c1, b_c1, w_c2, b_c2,
      hsum, outC);

  gemm_kernel<false><<<dim3(64, 4), dim3(256), 0, stream>>>(
      hsum, w_out, b_out, outF, nullptr, nullptr, 4096, 256, 256, 256, 256);
}

// Round 15
// 586.251 us; speedup vs baseline: 1.4556x; 1.1682x over previous
//
#include <hip/hip_runtime.h>
#include <hip/hip_fp16.h>
#include <float.h>
#include <math.h>

#define BB   2
#define NPTS 2048
#define NODES (BB*NPTS)   // 4096
#define NNB  32
#define NH   4
#define NDH  64

// padded LDS row strides (== 4 mod 32 words -> conflict-free broadcast groups)
#define SCR_LD  132
#define POS_LD   68
#define M_LD     68
#define E2T_LD  132

// ======================= KNN (exact numpy replication) =======================
__global__ __launch_bounds__(256) void knn_kernel(const float* __restrict__ coors,
    int* __restrict__ idx_out, float* __restrict__ dnb_out, float* __restrict__ rel_out) {
#pragma clang fp contract(off)
  const int node = blockIdx.x;
  const int b = node >> 11;
  const int i = node & (NPTS - 1);
  __shared__ float cx[NPTS], cy[NPTS], cz[NPTS];
  __shared__ float wdist[4]; __shared__ int wjj[4];
  __shared__ float win_d_s; __shared__ int win_j_s;
  __shared__ float sel_d[NNB]; __shared__ int sel_j[NNB];
  const float* cb = coors + (size_t)b * NPTS * 3;
  for (int j = threadIdx.x; j < NPTS; j += 256) {
    cx[j] = cb[3*j]; cy[j] = cb[3*j+1]; cz[j] = cb[3*j+2];
  }
  __syncthreads();
  const float xi = cx[i], yi = cy[i], zi = cz[i];
  float dl[8]; int jl[8];
  #pragma unroll
  for (int s = 0; s < 8; ++s) {
    int j = threadIdx.x + (s << 8);
    float dx = xi - cx[j];
    float dy = yi - cy[j];
    float dz = zi - cz[j];
    float ss = dx*dx + dy*dy;   // contract(off): matches numpy rounding
    ss = ss + dz*dz;
    dl[s] = sqrtf(ss);          // correctly rounded by default on HIP
    jl[s] = j;
  }
  for (int it = 0; it < NNB; ++it) {
    float bd = FLT_MAX; int bj = 0x7FFFFFFF;
    #pragma unroll
    for (int s = 0; s < 8; ++s)
      if (dl[s] < bd || (dl[s] == bd && jl[s] < bj)) { bd = dl[s]; bj = jl[s]; }
    #pragma unroll
    for (int off = 32; off > 0; off >>= 1) {
      float od = __shfl_down(bd, off, 64);
      int   oj = __shfl_down(bj, off, 64);
      if (od < bd || (od == bd && oj < bj)) { bd = od; bj = oj; }
    }
    if ((threadIdx.x & 63) == 0) { wdist[threadIdx.x >> 6] = bd; wjj[threadIdx.x >> 6] = bj; }
    __syncthreads();
    if (threadIdx.x == 0) {
      float fd = wdist[0]; int fj = wjj[0];
      #pragma unroll
      for (int w = 1; w < 4; ++w)
        if (wdist[w] < fd || (wdist[w] == fd && wjj[w] < fj)) { fd = wdist[w]; fj = wjj[w]; }
      win_d_s = fd; win_j_s = fj; sel_d[it] = fd; sel_j[it] = fj;
    }
    __syncthreads();
    const int wj = win_j_s;
    #pragma unroll
    for (int s = 0; s < 8; ++s) if (jl[s] == wj) dl[s] = FLT_MAX;
    __syncthreads();
  }
  if (threadIdx.x < NNB) {
    int s = threadIdx.x;
    int j = sel_j[s];
    idx_out[(size_t)node*NNB + s] = j;
    dnb_out[(size_t)node*NNB + s] = sel_d[s];
    float* rp = rel_out + ((size_t)node*NNB + s)*3;
    rp[0] = xi - cx[j]; rp[1] = yi - cy[j]; rp[2] = zi - cz[j];
  }
}

// ======================= generic f32 GEMM (64x64 tile) =======================
template<bool SPLIT>
__global__ __launch_bounds__(256) void gemm_kernel(const float* __restrict__ A,
    const float* __restrict__ Bm, const float* __restrict__ bias,
    float* __restrict__ C0, float* __restrict__ C1, float* __restrict__ C2,
    int Mn, int Nn, int Kn, int lda, int ldb) {
  __shared__ float As[64][17];
  __shared__ __align__(16) float Bs[16][64];
  const int bm = blockIdx.x * 64, bn = blockIdx.y * 64;
  const int tx = threadIdx.x & 15, ty = threadIdx.x >> 4;
  const int lm = threadIdx.x >> 2, lk = (threadIdx.x & 3) * 4;
  const int br = threadIdx.x >> 4, bc = (threadIdx.x & 15) * 4;
  float acc[4][4] = {};
  for (int k0 = 0; k0 < Kn; k0 += 16) {
    float4 av = *(const float4*)(A + (size_t)(bm + lm)*lda + k0 + lk);
    As[lm][lk+0] = av.x; As[lm][lk+1] = av.y; As[lm][lk+2] = av.z; As[lm][lk+3] = av.w;
    float4 bv = *(const float4*)(Bm + (size_t)(k0 + br)*ldb + bn + bc);
    *(float4*)&Bs[br][bc] = bv;
    __syncthreads();
    #pragma unroll
    for (int kk = 0; kk < 16; ++kk) {
      float a0 = As[ty*4+0][kk], a1 = As[ty*4+1][kk], a2 = As[ty*4+2][kk], a3 = As[ty*4+3][kk];
      float4 bq = *(const float4*)&Bs[kk][tx*4];
      acc[0][0] += a0*bq.x; acc[0][1] += a0*bq.y; acc[0][2] += a0*bq.z; acc[0][3] += a0*bq.w;
      acc[1][0] += a1*bq.x; acc[1][1] += a1*bq.y; acc[1][2] += a1*bq.z; acc[1][3] += a1*bq.w;
      acc[2][0] += a2*bq.x; acc[2][1] += a2*bq.y; acc[2][2] += a2*bq.z; acc[2][3] += a2*bq.w;
      acc[3][0] += a3*bq.x; acc[3][1] += a3*bq.y; acc[3][2] += a3*bq.z; acc[3][3] += a3*bq.w;
    }
    __syncthreads();
  }
  #pragma unroll
  for (int r = 0; r < 4; ++r) {
    #pragma unroll
    for (int c = 0; c < 4; ++c) {
      int row = bm + ty*4 + r, col = bn + tx*4 + c;
      float vv = acc[r][c];
      if (bias) vv += bias[col];
      if (SPLIT) {
        int w = col >> 8, cc = col & 255;
        float* Cp = (w == 0) ? C0 : ((w == 1) ? C1 : C2);
        Cp[(size_t)row*256 + cc] = vv;
      } else {
        C0[(size_t)row*Nn + col] = vv;
      }
    }
  }
}

// ======================= weight pack: row-pair half2 =======================
// w_p2 [128][64] -> p2h[kp<64][64]; w_e1 [64][128] -> e1h[kp<32][128];
// w_c1 [64][64] -> c1h[kp<32][64].  half2 = (row 2kp, row 2kp+1).
__global__ __launch_bounds__(256) void pack_kernel(const float* __restrict__ w_p2,
    const float* __restrict__ w_e1, const float* __restrict__ w_c1,
    __half2* __restrict__ p2h, __half2* __restrict__ e1h, __half2* __restrict__ c1h) {
  int i = blockIdx.x * 256 + threadIdx.x;   // grid 16x256 = 4096
  if (i < 4096) {
    int kp = i >> 6, c = i & 63;
    p2h[i] = __floats2half2_rn(w_p2[(2*kp)*64 + c], w_p2[(2*kp+1)*64 + c]);
  }
  if (i < 4096) {
    int kp = i >> 7, c = i & 127;
    e1h[i] = __floats2half2_rn(w_e1[(2*kp)*128 + c], w_e1[(2*kp+1)*128 + c]);
  }
  if (i < 2048) {
    int kp = i >> 6, c = i & 63;
    c1h[i] = __floats2half2_rn(w_c1[(2*kp)*64 + c], w_c1[(2*kp+1)*64 + c]);
  }
}

// ======================= fused per-node kernel =======================
// block = one node, 512 threads = 8 waves. 53,888 B dynamic LDS.
// WAVE-OWNS-NEIGHBORS (R14 structure, 4 barriers) + half2-packed weight GEMVs:
// each 16B load delivers 8 weights (2 k-rows x 4 cols) -> weight-stream bytes
// and load count halved vs R14 (320 -> 160 wide loads/thread).
__global__ __launch_bounds__(512, 4) void fused_kernel(
    const int* __restrict__ idx, const float* __restrict__ dnb, const float* __restrict__ relnb,
    const float* __restrict__ qe, const float* __restrict__ ke, const float* __restrict__ v,
    const float* __restrict__ w_p1, const float* __restrict__ b_p1,
    const __half2* __restrict__ w_p2h, const float* __restrict__ b_p2,
    const __half2* __restrict__ w_e1h, const float* __restrict__ w_e2, const float* __restrict__ b_e2,
    const float* __restrict__ w_a1, const float* __restrict__ b_a1,
    const float* __restrict__ w_a2, const float* __restrict__ b_a2,
    const __half2* __restrict__ w_c1h, const float* __restrict__ b_c1,
    const float* __restrict__ w_c2, const float* __restrict__ b_c2,
    float* __restrict__ hsum, float* __restrict__ coors_out) {
  extern __shared__ float sm[];
  float* w_e2Ts= sm;               // 16*132 = 2112 (transposed)
  float* w_a1s = w_e2Ts + 2112;    // 1024
  float* qe_s  = w_a1s + 1024;     // 512
  float* fe_s  = qe_s + 512;       // 288
  float* pos_s = fe_s + 288;       // 32*68  = 2176
  float* scr   = pos_s + 2176;     // 32*132 = 4224 (ph / h1e per-wave rows)
  float* m_all = scr + 4224;       // 32*68  = 2176
  float* sim_s = m_all + 2176;     // 128
  float* attn_s= sim_s + 128;      // 128
  float* part_s= attn_s + 128;     // 512
  float* cw_s  = part_s + 512;     // 32
  float* dnb_s = cw_s + 32;        // 32
  float* rel_s = dnb_s + 32;       // 96
  int*   idx_s = (int*)(rel_s + 96); // 32  -> total 13472 floats = 53,888 B
  const int t = threadIdx.x;
  const int node = blockIdx.x;
  const int b = node >> 11;
  const int w   = t >> 6;          // wave 0..7
  const int l   = t & 63;          // lane 0..63
  const int jw  = (w << 2) | (l >> 4);   // this lane's neighbor row (4 per wave)
  const int l16 = l & 15;

  // ---- stage LDS-resident data ----
  for (int i = t; i < 2048; i += 512) {            // transpose w_e2 [128][16] -> [16][132]
    int kx = i >> 4, mt = i & 15;
    w_e2Ts[mt*E2T_LD + kx] = w_e2[i];
  }
  for (int i = t; i < 1024; i += 512) w_a1s[i] = w_a1[i];
  qe_s[t] = qe[(size_t)node*512 + t];
  if (t < NNB) { idx_s[t] = idx[(size_t)node*NNB + t]; dnb_s[t] = dnb[(size_t)node*NNB + t]; }
  if (t >= 64 && t < 64 + NNB*3) rel_s[t-64] = relnb[(size_t)node*NNB*3 + (t-64)];
  __syncthreads();   // B1: staged weights/qe/idx/dnb/rel visible to all waves

  // ---- P1a: fourier features, lanes 0..3 of each wave do own rows ----
  if (l < 4) {
    int jj = (w << 2) | l;
    float d = dnb_s[jj];
    float* f = fe_s + jj*9;
    f[0] = sinf(d);          f[1] = sinf(d*0.5f);
    f[2] = sinf(d*0.25f);    f[3] = sinf(d*0.125f);
    f[4] = cosf(d);          f[5] = cosf(d*0.5f);
    f[6] = cosf(d*0.25f);    f[7] = cosf(d*0.125f);
    f[8] = d;
  }
  // in-wave dep: fe_s rows 4w..4w+3 read below by same wave only

  // ---- P1b: ph = relu(fe @ w_p1 + b_p1) -> scr[jw][o8..o8+7] ; f32 ----
  {
    const int o8 = l16*8;
    float4 a0 = *(const float4*)(b_p1 + o8);
    float4 a1 = *(const float4*)(b_p1 + o8 + 4);
    #pragma unroll
    for (int r = 0; r < 9; ++r) {
      float fr = fe_s[jw*9 + r];
      float4 w0 = *(const float4*)(w_p1 + r*128 + o8);
      float4 w1 = *(const float4*)(w_p1 + r*128 + o8 + 4);
      a0.x += fr*w0.x; a0.y += fr*w0.y; a0.z += fr*w0.z; a0.w += fr*w0.w;
      a1.x += fr*w1.x; a1.y += fr*w1.y; a1.z += fr*w1.z; a1.w += fr*w1.w;
    }
    a0.x = fmaxf(a0.x,0.f); a0.y = fmaxf(a0.y,0.f); a0.z = fmaxf(a0.z,0.f); a0.w = fmaxf(a0.w,0.f);
    a1.x = fmaxf(a1.x,0.f); a1.y = fmaxf(a1.y,0.f); a1.z = fmaxf(a1.z,0.f); a1.w = fmaxf(a1.w,0.f);
    *(float4*)(scr + jw*SCR_LD + o8)     = a0;
    *(float4*)(scr + jw*SCR_LD + o8 + 4) = a1;
  }

  // ---- P1c: pos = ph @ w_p2 + b_p2 (half2 row-pairs) -> pos_s[jw][og..] ----
  {
    const int og = l16*4;
    const float* ph = scr + jw*SCR_LD;
    float s0=0,s1=0,s2=0,s3=0;
    #pragma unroll 4
    for (int kp = 0; kp < 64; ++kp) {
      float2 p = *(const float2*)(ph + 2*kp);          // rows 2kp, 2kp+1
      float4 wv = *(const float4*)(w_p2h + kp*64 + og); // 4 half2 cols og..og+3
      const __half2* hp = (const __half2*)&wv;
      float2 c0 = __half22float2(hp[0]);
      float2 c1 = __half22float2(hp[1]);
      float2 c2 = __half22float2(hp[2]);
      float2 c3 = __half22float2(hp[3]);
      s0 += p.x*c0.x; s0 += p.y*c0.y;
      s1 += p.x*c1.x; s1 += p.y*c1.y;
      s2 += p.x*c2.x; s2 += p.y*c2.y;
      s3 += p.x*c3.x; s3 += p.y*c3.y;
    }
    float4 bp = *(const float4*)(b_p2 + og);
    pos_s[jw*POS_LD+og+0] = bp.x + s0;
    pos_s[jw*POS_LD+og+1] = bp.y + s1;
    pos_s[jw*POS_LD+og+2] = bp.z + s2;
    pos_s[jw*POS_LD+og+3] = bp.w + s3;
  }

  // ---- P2: pose = pos @ w_e1 (half2 row-pairs) -> registers pr[8] ----
  float pr[8];
  {
    const int o8 = l16*8;
    const float* pj = pos_s + jw*POS_LD;
    float s0=0,s1=0,s2=0,s3=0,s4=0,s5=0,s6=0,s7=0;
    #pragma unroll 4
    for (int kp = 0; kp < 32; ++kp) {
      float2 p = *(const float2*)(pj + 2*kp);
      float4 wv0 = *(const float4*)(w_e1h + kp*128 + o8);
      float4 wv1 = *(const float4*)(w_e1h + kp*128 + o8 + 4);
      const __half2* h0 = (const __half2*)&wv0;
      const __half2* h1 = (const __half2*)&wv1;
      float2 c0 = __half22float2(h0[0]), c1 = __half22float2(h0[1]);
      float2 c2 = __half22float2(h0[2]), c3 = __half22float2(h0[3]);
      float2 c4 = __half22float2(h1[0]), c5 = __half22float2(h1[1]);
      float2 c6 = __half22float2(h1[2]), c7 = __half22float2(h1[3]);
      s0 += p.x*c0.x; s0 += p.y*c0.y;  s1 += p.x*c1.x; s1 += p.y*c1.y;
      s2 += p.x*c2.x; s2 += p.y*c2.y;  s3 += p.x*c3.x; s3 += p.y*c3.y;
      s4 += p.x*c4.x; s4 += p.y*c4.y;  s5 += p.x*c5.x; s5 += p.y*c5.y;
      s6 += p.x*c6.x; s6 += p.y*c6.y;  s7 += p.x*c7.x; s7 += p.y*c7.y;
    }
    pr[0]=s0; pr[1]=s1; pr[2]=s2; pr[3]=s3; pr[4]=s4; pr[5]=s5; pr[6]=s6; pr[7]=s7;
  }

  // ---- P3: per head: h1e = relu(qe - ke + pose) -> scr[jw]; GEMV -> m_all ----
  {
    const size_t kebase = ((size_t)((b << 11) + idx_s[jw])*NH)*128;
    const int o8 = l16*8;
    for (int h = 0; h < NH; ++h) {
      float4 kv0 = *(const float4*)(ke + kebase + h*128 + o8);
      float4 kv1 = *(const float4*)(ke + kebase + h*128 + o8 + 4);
      float4 qv0 = *(const float4*)(qe_s + h*128 + o8);
      float4 qv1 = *(const float4*)(qe_s + h*128 + o8 + 4);
      float4 h0, h1;
      h0.x = fmaxf(qv0.x - kv0.x + pr[0], 0.f);
      h0.y = fmaxf(qv0.y - kv0.y + pr[1], 0.f);
      h0.z = fmaxf(qv0.z - kv0.z + pr[2], 0.f);
      h0.w = fmaxf(qv0.w - kv0.w + pr[3], 0.f);
      h1.x = fmaxf(qv1.x - kv1.x + pr[4], 0.f);
      h1.y = fmaxf(qv1.y - kv1.y + pr[5], 0.f);
      h1.z = fmaxf(qv1.z - kv1.z + pr[6], 0.f);
      h1.w = fmaxf(qv1.w - kv1.w + pr[7], 0.f);
      *(float4*)(scr + jw*SCR_LD + o8)     = h0;
      *(float4*)(scr + jw*SCR_LD + o8 + 4) = h1;
      // GEMV: one output (jw, mt=l16); in-wave dep on scr row jw
      const float* hp = scr + jw*SCR_LD;
      const float* wt = w_e2Ts + l16*E2T_LD;
      float s0=0,s1=0,s2=0,s3=0;
      #pragma unroll 8
      for (int kx = 0; kx < 128; kx += 4) {
        float4 hv = *(const float4*)(hp + kx);
        float4 wv = *(const float4*)(wt + kx);
        s0 += hv.x*wv.x; s1 += hv.y*wv.y; s2 += hv.z*wv.z; s3 += hv.w*wv.w;
      }
      m_all[jw*M_LD + h*16 + l16] = fmaxf(b_e2[l16] + ((s0+s1)+(s2+s3)), 0.0f);
    }
  }

  // ---- P4a: sim, wave-local: lane = (jl, h, qq); shfl-reduce over qq ----
  {
    const int jj = (w << 2) | (l >> 4);
    const int hh = (l >> 2) & 3, qq = l & 3;
    float mreg[16];
    #pragma unroll
    for (int mt = 0; mt < 16; ++mt) mreg[mt] = m_all[jj*M_LD + hh*16 + mt];
    float acc = 0.0f;
    #pragma unroll
    for (int oi = 0; oi < 16; ++oi) {
      int oo = qq*16 + oi;
      float ah = b_a1[oo];
      #pragma unroll
      for (int mt = 0; mt < 16; ++mt) ah += mreg[mt] * w_a1s[mt*64 + oo];
      acc += fmaxf(ah, 0.0f) * w_a2[oo];
    }
    acc += __shfl_down(acc, 2, 4);
    acc += __shfl_down(acc, 1, 4);
    if (qq == 0) sim_s[hh*32 + jj] = acc + b_a2[0];
  }

  // ---- P4b: coor MLP wave-local (half2 row-pairs): cw via shfl-reduce ----
  {
    const int og = l16*4;
    const float* mj = m_all + jw*M_LD;
    float s0=0,s1=0,s2=0,s3=0;
    #pragma unroll 4
    for (int kp = 0; kp < 32; ++kp) {
      float2 m = *(const float2*)(mj + 2*kp);
      float4 wv = *(const float4*)(w_c1h + kp*64 + og);
      const __half2* hp = (const __half2*)&wv;
      float2 c0 = __half22float2(hp[0]);
      float2 c1 = __half22float2(hp[1]);
      float2 c2 = __half22float2(hp[2]);
      float2 c3 = __half22float2(hp[3]);
      s0 += m.x*c0.x; s0 += m.y*c0.y;
      s1 += m.x*c1.x; s1 += m.y*c1.y;
      s2 += m.x*c2.x; s2 += m.y*c2.y;
      s3 += m.x*c3.x; s3 += m.y*c3.y;
    }
    float4 bc = *(const float4*)(b_c1 + og);
    float c0 = fmaxf(bc.x + s0, 0.f), c1 = fmaxf(bc.y + s1, 0.f);
    float c2 = fmaxf(bc.z + s2, 0.f), c3 = fmaxf(bc.w + s3, 0.f);
    float4 wc = *(const float4*)(w_c2 + og);
    float part = ((c0*wc.x + c1*wc.y) + (c2*wc.z + c3*wc.w));
    part += __shfl_down(part, 8, 16);
    part += __shfl_down(part, 4, 16);
    part += __shfl_down(part, 2, 16);
    part += __shfl_down(part, 1, 16);
    if (l16 == 0) cw_s[jw] = part + b_c2[0];
  }
  __syncthreads();   // B2: sim_s, cw_s, pos_s (all rows) now visible block-wide

  // ---- coors_out (lanes 64..66) and softmax (lanes 0..3), concurrent ----
  if (t >= 64 && t < 67) {
    int c = t - 64;
    float acc = 0.0f;
    for (int j = 0; j < 32; ++j) acc += cw_s[j] * rel_s[j*3 + c];
    coors_out[(size_t)node*3 + c] = acc;
  }
  if (t < 4) {   // softmax over j, faithful to reference
    const float* sp = sim_s + t*32;
    float mx = sp[0];
    for (int j = 1; j < 32; ++j) mx = fmaxf(mx, sp[j]);
    float s = 0.0f; float* ap = attn_s + t*32;
    for (int j = 0; j < 32; ++j) { float e = expf(sp[j] - mx); ap[j] = e; s += e; }
    for (int j = 0; j < 32; ++j) ap[j] = ap[j] / s;
  }
  __syncthreads();   // B3: attn_s visible

  // ---- P5a: attention output, full width: (jhalf, h, dd) per thread ----
  {
    int jh = t >> 8, h = (t >> 6) & 3, dd = t & 63;
    float acc = 0.0f;
    #pragma unroll
    for (int jj = 0; jj < 16; ++jj) {
      int j = jh*16 + jj;
      float vv = v[(size_t)((b << 11) + idx_s[j])*256 + h*64 + dd] + pos_s[j*POS_LD + dd];
      acc += attn_s[h*32 + j] * vv;
    }
    part_s[t] = acc;
  }
  __syncthreads();   // B4
  if (t < 256) hsum[(size_t)node*256 + t] = part_s[t] + part_s[t + 256];
}

// ======================= launch =======================
extern "C" void kernel_launch(void* const* d_in, const int* in_sizes, int n_in,
                              void* d_out, int out_size, void* d_ws, size_t ws_size,
                              hipStream_t stream) {
  const float* feats = (const float*)d_in[0];
  const float* coors = (const float*)d_in[1];
  const float* w_qkv = (const float*)d_in[2];
  const float* w_out = (const float*)d_in[3];
  const float* b_out = (const float*)d_in[4];
  const float* w_p1  = (const float*)d_in[5];
  const float* b_p1  = (const float*)d_in[6];
  const float* w_p2  = (const float*)d_in[7];
  const float* b_p2  = (const float*)d_in[8];
  const float* w_e1  = (const float*)d_in[9];
  const float* b_e1  = (const float*)d_in[10];
  const float* w_e2  = (const float*)d_in[11];
  const float* b_e2  = (const float*)d_in[12];
  const float* w_a1  = (const float*)d_in[13];
  const float* b_a1  = (const float*)d_in[14];
  const float* w_a2  = (const float*)d_in[15];
  const float* b_a2  = (const float*)d_in[16];
  const float* w_c1  = (const float*)d_in[17];
  const float* b_c1  = (const float*)d_in[18];
  const float* w_c2  = (const float*)d_in[19];
  const float* b_c2  = (const float*)d_in[20];

  float* ws   = (float*)d_ws;
  float* q    = ws;                 // 4096*256
  float* k    = q   + 1048576;
  float* v    = k   + 1048576;
  float* qe   = v   + 1048576;      // 16384*128 (incl. +b_e1)
  float* ke   = qe  + 2097152;
  float* hsum = ke  + 2097152;      // 4096*256
  int*   idx  = (int*)(hsum + 1048576);   // 4096*32
  float* dnb  = (float*)(idx + 131072);
  float* reln = dnb + 131072;       // 4096*32*3
  __half2* p2h = (__half2*)(reln + 393216);   // 4096 half2
  __half2* e1h = p2h + 4096;                  // 4096 half2
  __half2* c1h = e1h + 4096;                  // 2048 half2

  float* outF = (float*)d_out;              // (B,N,256)
  float* outC = outF + (size_t)NODES*256;   // (B,N,3)

  pack_kernel<<<dim3(16), dim3(256), 0, stream>>>(w_p2, w_e1, w_c1, p2h, e1h, c1h);

  knn_kernel<<<dim3(NODES), dim3(256), 0, stream>>>(coors, idx, dnb, reln);

  gemm_kernel<true><<<dim3(64, 12), dim3(256), 0, stream>>>(
      feats, w_qkv, nullptr, q, k, v, 4096, 768, 256, 256, 768);

  gemm_kernel<false><<<dim3(256, 2), dim3(256), 0, stream>>>(
      q, w_e1, b_e1, qe, nullptr, nullptr, 16384, 128, 64, 64, 128);
  gemm_kernel<false><<<dim3(256, 2), dim3(256), 0, stream>>>(
      k, w_e1, nullptr, ke, nullptr, nullptr, 16384, 128, 64, 64, 128);

  constexpr int FUSED_SMEM = 13472 * 4;   // 53,888 B dynamic LDS
  (void)hipFuncSetAttribute(reinterpret_cast<const void*>(fused_kernel),
                            hipFuncAttributeMaxDynamicSharedMemorySize, FUSED_SMEM);
  fused_kernel<<<dim3(NODES), dim3(512), FUSED_SMEM, stream>>>(
      idx, dnb, reln, qe, ke, v,
      w_p1, b_p1, p2h, b_p2, e1h, w_e2, b_e2,
      w_a1, b_a1, w_a2, b_a2, c1h, b_c1, w_c2, b_c2,
      hsum, outC);

  gemm_kernel<false><<<dim3(64, 4), dim3(256), 0, stream>>>(
      hsum, w_out, b_out, outF, nullptr, nullptr, 4096, 256, 256, 256, 256);
}